// Round 14
// baseline (626.071 us; speedup 1.0000x reference)
//
#include <hip/hip_runtime.h>

#define N_NODES 20000
#define N_EDGES 640000
#define FDIM 64
#define NB 20
#define LN_EPS 1e-5f
#define NW 8

typedef __attribute__((ext_vector_type(8))) short bf16x8;
typedef __attribute__((ext_vector_type(4))) float f32x4;

#define SEL_HI 0x07060302u
#define SEL_LO 0x05040100u
#define MFMA16 __builtin_amdgcn_mfma_f32_16x16x32_bf16

__device__ __forceinline__ float silu_f(float x) { return x / (1.0f + __expf(-x)); }

__device__ __forceinline__ float bcast_lane(float v, int lane) {
    return __int_as_float(__builtin_amdgcn_readlane(__float_as_int(v), lane));
}

__device__ __forceinline__ unsigned bf16_rn(float x) {
    unsigned u = __float_as_uint(x);
    return (u + 0x7FFFu + ((u >> 16) & 1u)) >> 16;
}

__device__ __forceinline__ unsigned pack_split(float x) {
    unsigned h = bf16_rn(x);
    unsigned lo = bf16_rn(x - __uint_as_float(h << 16));
    return (h << 16) | lo;
}

__device__ __forceinline__ void load_afrag(const unsigned* rowPtr, int kh, int q,
                                           bf16x8* ahi, bf16x8* alo) {
    const uint4 ra = *(const uint4*)(rowPtr + kh * 32 + q * 8);
    const uint4 rb = *(const uint4*)(rowPtr + kh * 32 + q * 8 + 4);
    union { unsigned u[4]; bf16x8 v; } H, L;
    H.u[0] = __builtin_amdgcn_perm(ra.y, ra.x, SEL_HI);
    H.u[1] = __builtin_amdgcn_perm(ra.w, ra.z, SEL_HI);
    H.u[2] = __builtin_amdgcn_perm(rb.y, rb.x, SEL_HI);
    H.u[3] = __builtin_amdgcn_perm(rb.w, rb.z, SEL_HI);
    L.u[0] = __builtin_amdgcn_perm(ra.y, ra.x, SEL_LO);
    L.u[1] = __builtin_amdgcn_perm(ra.w, ra.z, SEL_LO);
    L.u[2] = __builtin_amdgcn_perm(rb.y, rb.x, SEL_LO);
    L.u[3] = __builtin_amdgcn_perm(rb.w, rb.z, SEL_LO);
    *ahi = H.v;
    *alo = L.v;
}

__device__ __forceinline__ void mm3(const unsigned* Bhi, const unsigned* Blo,
                                    bf16x8 ahi, bf16x8 alo, f32x4* acc, int kh, int l) {
#pragma unroll
    for (int c = 0; c < 4; ++c) {
        bf16x8 bh = *(const bf16x8*)(Bhi + (kh * 4 + c) * 256 + l * 4);
        bf16x8 bl = *(const bf16x8*)(Blo + (kh * 4 + c) * 256 + l * 4);
        acc[c] = MFMA16(ahi, bh, acc[c], 0, 0, 0);
        acc[c] = MFMA16(ahi, bl, acc[c], 0, 0, 0);
        acc[c] = MFMA16(alo, bh, acc[c], 0, 0, 0);
    }
}

// ---------------- Kernel A: node MLP ----------------
__global__ __launch_bounds__(256) void node_mlp_kernel(
    const float* __restrict__ atom, const float* __restrict__ W1, const float* __restrict__ b1,
    const float* __restrict__ W2, const float* __restrict__ b2, float* __restrict__ mn)
{
    __shared__ float W1s[FDIM][FDIM];
    __shared__ float W2s[FDIM][FDIM];
    const int f = threadIdx.x, ty = threadIdx.y;
    const int tid = ty * 64 + f;
    for (int i = tid; i < FDIM * FDIM; i += 256) {
        ((float*)W1s)[i] = W1[i];
        ((float*)W2s)[i] = W2[i];
    }
    __syncthreads();
    const float bb1 = b1[f], bb2 = b2[f];
    const int nw = gridDim.x * 4;
    for (int n = blockIdx.x * 4 + ty; n < N_NODES; n += nw) {
        const float a = atom[n * FDIM + f];
        float h = bb1;
        for (int g = 0; g < FDIM; ++g) h += bcast_lane(a, g) * W1s[g][f];
        h = silu_f(h);
        float o = bb2;
        for (int g = 0; g < FDIM; ++g) o += bcast_lane(h, g) * W2s[g][f];
        mn[n * FDIM + f] = o;
    }
}

// ---------------- CSR build ----------------
__global__ __launch_bounds__(256) void hist_kernel(const int* __restrict__ eidx, int* __restrict__ cursor) {
    for (int e = blockIdx.x * 256 + threadIdx.x; e < N_EDGES; e += gridDim.x * 256)
        atomicAdd(&cursor[eidx[e]], 1);
}

__global__ __launch_bounds__(1024) void scan_kernel(int* __restrict__ cursor, int* __restrict__ rowStart) {
    __shared__ int part[1024];
    const int t = threadIdx.x;
    int loc[20];
    int s = 0;
#pragma unroll
    for (int i = 0; i < 20; ++i) {
        const int idx = t * 20 + i;
        const int v = (idx < N_NODES) ? cursor[idx] : 0;
        loc[i] = s;
        s += v;
    }
    part[t] = s;
    __syncthreads();
    for (int off = 1; off < 1024; off <<= 1) {
        int v = (t >= off) ? part[t - off] : 0;
        __syncthreads();
        part[t] += v;
        __syncthreads();
    }
    const int excl = (t == 0) ? 0 : part[t - 1];
#pragma unroll
    for (int i = 0; i < 20; ++i) {
        const int idx = t * 20 + i;
        if (idx < N_NODES) {
            cursor[idx] = excl + loc[i];
            rowStart[idx] = excl + loc[i];
        }
    }
    if (t == 1023) rowStart[N_NODES] = part[1023];
}

__global__ __launch_bounds__(256) void permute_kernel(
    const int* __restrict__ eidx, const float* __restrict__ dir,
    int* __restrict__ cursor, int* __restrict__ invperm, uint4* __restrict__ meta)
{
    for (int e = blockIdx.x * 256 + threadIdx.x; e < N_EDGES; e += gridDim.x * 256) {
        const int src = eidx[e];
        const int dst = eidx[N_EDGES + e];
        const int pos = atomicAdd(&cursor[src], 1);
        invperm[e] = pos;
        uint4 m;
        m.x = (unsigned)dst;
        m.y = __float_as_uint(dir[e * 3 + 0]);
        m.z = __float_as_uint(dir[e * 3 + 1]);
        m.w = __float_as_uint(dir[e * 3 + 2]);
        meta[pos] = m;
    }
}

// ---------------- P1: edge kernel — MFMA pipeline, e1/e2 STORED (no force atomics) ----------------
__global__ __launch_bounds__(64 * NW, 2) void edge_p1_kernel(
    const float* __restrict__ dist, const int* __restrict__ eidx,
    const int* __restrict__ invperm,
    const float* __restrict__ mn, const float* __restrict__ We,
    const float* __restrict__ Wq1a, const float* __restrict__ Wq1b,
    const float* __restrict__ Wq2a, const float* __restrict__ Wq2b,
    float* __restrict__ atomAcc, float* __restrict__ e1a, float* __restrict__ e2a)
{
    __shared__ __align__(16) unsigned Bfr[16384];
    __shared__ __align__(16) unsigned WeFr[2048];
    __shared__ __align__(16) unsigned Astg[NW][16][76];

    const int l = threadIdx.x;
    const int ty = threadIdx.y;
    const int q = l >> 4, row = l & 15;

    for (int t = ty; t < 32; t += NW) {
        const int mm = t >> 3, kh = (t >> 2) & 1, c = t & 3;
        const float* W = (mm == 0) ? Wq1a : (mm == 1) ? Wq2a : (mm == 2) ? Wq1b : Wq2b;
        const int n = c * 16 + row;
        const int kb = kh * 32 + q * 8;
        unsigned* hiP = &Bfr[(((mm * 2 + 0) * 2 + kh) * 4 + c) * 256 + l * 4];
        unsigned* loP = &Bfr[(((mm * 2 + 1) * 2 + kh) * 4 + c) * 256 + l * 4];
#pragma unroll
        for (int i = 0; i < 4; ++i) {
            float w0 = W[(kb + 2 * i) * FDIM + n];
            float w1 = W[(kb + 2 * i + 1) * FDIM + n];
            unsigned h0 = bf16_rn(w0);
            unsigned l0 = bf16_rn(w0 - __uint_as_float(h0 << 16));
            unsigned h1 = bf16_rn(w1);
            unsigned l1 = bf16_rn(w1 - __uint_as_float(h1 << 16));
            hiP[i] = h0 | (h1 << 16);
            loP[i] = l0 | (l1 << 16);
        }
    }
    for (int c = ty; c < 4; c += NW) {
        const int n = c * 16 + row;
        unsigned* hiP = &WeFr[(0 * 4 + c) * 256 + l * 4];
        unsigned* loP = &WeFr[(1 * 4 + c) * 256 + l * 4];
#pragma unroll
        for (int i = 0; i < 4; ++i) {
            const int k0 = q * 8 + 2 * i, k1 = k0 + 1;
            float w0 = (k0 < NB) ? We[k0 * FDIM + n] : 0.0f;
            float w1 = (k1 < NB) ? We[k1 * FDIM + n] : 0.0f;
            unsigned h0 = bf16_rn(w0);
            unsigned l0 = bf16_rn(w0 - __uint_as_float(h0 << 16));
            unsigned h1 = bf16_rn(w1);
            unsigned l1 = bf16_rn(w1 - __uint_as_float(h1 << 16));
            hiP[i] = h0 | (h1 << 16);
            loP[i] = l0 | (l1 << 16);
        }
    }
    __syncthreads();

    const unsigned* B1aH = Bfr + 0 * 2048; const unsigned* B1aL = Bfr + 1 * 2048;
    const unsigned* B2aH = Bfr + 2 * 2048; const unsigned* B2aL = Bfr + 3 * 2048;
    const unsigned* B1bH = Bfr + 4 * 2048; const unsigned* B1bL = Bfr + 5 * 2048;
    const unsigned* B2bH = Bfr + 6 * 2048; const unsigned* B2bL = Bfr + 7 * 2048;
    const unsigned* WeH = WeFr;            const unsigned* WeL = WeFr + 1024;

    unsigned* stg = &Astg[ty][0][0];
    const unsigned* rowPtr = &Astg[ty][row][0];

    const int ngroups = N_EDGES / 16;
    const int stride = gridDim.x * NW;
    for (int grp = blockIdx.x * NW + ty; grp < ngroups; grp += stride) {
        const int e0 = grp * 16;

        int ev = 0;
        if (l < 32) ev = eidx[(l < 16) ? (e0 + l) : (N_EDGES + e0 + (l - 16))];
        const int pos = (l < 16) ? invperm[e0 + l] : 0;

        // me = dist @ We via MFMA
        const float* dp = dist + (size_t)(e0 + row) * NB + q * 8;
        float4 da = {0.f, 0.f, 0.f, 0.f}, db = {0.f, 0.f, 0.f, 0.f};
        if (q < 2)       { da = *(const float4*)dp; db = *(const float4*)(dp + 4); }
        else if (q == 2) { da = *(const float4*)dp; }
        unsigned s0 = pack_split(da.x), s1 = pack_split(da.y);
        unsigned s2 = pack_split(da.z), s3 = pack_split(da.w);
        unsigned s4 = pack_split(db.x), s5 = pack_split(db.y);
        unsigned s6 = pack_split(db.z), s7 = pack_split(db.w);
        union { unsigned u[4]; bf16x8 v; } AH, AL;
        AH.u[0] = __builtin_amdgcn_perm(s1, s0, SEL_HI);
        AH.u[1] = __builtin_amdgcn_perm(s3, s2, SEL_HI);
        AH.u[2] = __builtin_amdgcn_perm(s5, s4, SEL_HI);
        AH.u[3] = __builtin_amdgcn_perm(s7, s6, SEL_HI);
        AL.u[0] = __builtin_amdgcn_perm(s1, s0, SEL_LO);
        AL.u[1] = __builtin_amdgcn_perm(s3, s2, SEL_LO);
        AL.u[2] = __builtin_amdgcn_perm(s5, s4, SEL_LO);
        AL.u[3] = __builtin_amdgcn_perm(s7, s6, SEL_LO);

        f32x4 me4[4];
#pragma unroll
        for (int c = 0; c < 4; ++c) me4[c] = (f32x4){0.f, 0.f, 0.f, 0.f};
        mm3(WeH, WeL, AH.v, AL.v, me4, 0, l);
#pragma unroll
        for (int c = 0; c < 4; ++c)
#pragma unroll
            for (int r = 0; r < 4; ++r)
                stg[(q * 4 + r) * 76 + (row + 16 * c)] = __float_as_uint(me4[c][r]);

        // pass A: mn gathers only
        float p[16];
#pragma unroll
        for (int j = 0; j < 16; ++j) {
            const int src = __builtin_amdgcn_readlane(ev, j);
            const int dst = __builtin_amdgcn_readlane(ev, 16 + j);
            p[j] = mn[(size_t)src * FDIM + l] * mn[(size_t)dst * FDIM + l];
        }
        // pass B: atomAcc atomics only
#pragma unroll
        for (int j = 0; j < 16; ++j) {
            const int src = __builtin_amdgcn_readlane(ev, j);
            const float m = __uint_as_float(stg[j * 76 + l]) * p[j];
            atomicAdd(&atomAcc[(size_t)src * FDIM + l], m);
            stg[j * 76 + l] = pack_split(m);
        }

        // h-phase
        f32x4 acc1[4], acc2[4];
#pragma unroll
        for (int c = 0; c < 4; ++c) {
            acc1[c] = (f32x4){0.f, 0.f, 0.f, 0.f};
            acc2[c] = (f32x4){0.f, 0.f, 0.f, 0.f};
        }
#pragma unroll
        for (int kh = 0; kh < 2; ++kh) {
            bf16x8 ahi, alo;
            load_afrag(rowPtr, kh, q, &ahi, &alo);
            mm3(B1aH, B1aL, ahi, alo, acc1, kh, l);
            mm3(B2aH, B2aL, ahi, alo, acc2, kh, l);
        }
#pragma unroll
        for (int c = 0; c < 4; ++c)
#pragma unroll
            for (int r = 0; r < 4; ++r) {
                acc1[c][r] = silu_f(acc1[c][r]);
                acc2[c][r] = silu_f(acc2[c][r]);
            }

        // e1 = h1@Wq1b
#pragma unroll
        for (int c = 0; c < 4; ++c)
#pragma unroll
            for (int r = 0; r < 4; ++r)
                stg[(q * 4 + r) * 76 + (row + 16 * c)] = pack_split(acc1[c][r]);
        f32x4 eacc1[4];
#pragma unroll
        for (int c = 0; c < 4; ++c) eacc1[c] = (f32x4){0.f, 0.f, 0.f, 0.f};
#pragma unroll
        for (int kh = 0; kh < 2; ++kh) {
            bf16x8 ahi, alo;
            load_afrag(rowPtr, kh, q, &ahi, &alo);
            mm3(B1bH, B1bL, ahi, alo, eacc1, kh, l);
        }

        // e2 = h2@Wq2b
#pragma unroll
        for (int c = 0; c < 4; ++c)
#pragma unroll
            for (int r = 0; r < 4; ++r)
                stg[(q * 4 + r) * 76 + (row + 16 * c)] = pack_split(acc2[c][r]);
        f32x4 eacc2[4];
#pragma unroll
        for (int c = 0; c < 4; ++c) eacc2[c] = (f32x4){0.f, 0.f, 0.f, 0.f};
#pragma unroll
        for (int kh = 0; kh < 2; ++kh) {
            bf16x8 ahi, alo;
            load_afrag(rowPtr, kh, q, &ahi, &alo);
            mm3(B2bH, B2bL, ahi, alo, eacc2, kh, l);
        }

        // store e1/e2 rows at CSR-sorted position (plain stores, no atomics)
#pragma unroll
        for (int r = 0; r < 4; ++r) {
            const int eo = q * 4 + r;
            const int po = __shfl(pos, eo);
            float* p1 = e1a + (size_t)po * FDIM;
            float* p2 = e2a + (size_t)po * FDIM;
#pragma unroll
            for (int c = 0; c < 4; ++c) {
                const int n = row + 16 * c;
                p1[n] = eacc1[c][r];
                p2[n] = eacc2[c][r];
            }
        }
    }
}

// ---------------- P2: node kernel — gather + reduce + fused inv2/LN (no atomics) ----------------
__global__ __launch_bounds__(512) void node_p2_kernel(
    const float* __restrict__ forceN,     // original force_node [N,3,F]
    const float* __restrict__ Wu, const float* __restrict__ gamma, const float* __restrict__ beta,
    const uint4* __restrict__ meta,       // [E] {dst,d0,d1,d2} at sorted pos
    const int* __restrict__ rowStart,     // [N+1]
    const float* __restrict__ e1a, const float* __restrict__ e2a,
    float* __restrict__ atomOut,          // [N,F]: atom_node + inv1 (from P1 atomics)
    float* __restrict__ forceOut)         // [N,3,F]
{
    __shared__ float Wus[FDIM][FDIM];
    const int l = threadIdx.x, ty = threadIdx.y;
    const int tid = ty * 64 + l;
    for (int i = tid; i < FDIM * FDIM; i += 512) ((float*)Wus)[i] = Wu[i];
    __syncthreads();
    const float gg = gamma[l], bb = beta[l];
    const int nwv = gridDim.x * 8;
    for (int v = blockIdx.x * 8 + ty; v < N_NODES; v += nwv) {
        const int s = rowStart[v], e = rowStart[v + 1];
        float a0 = forceN[(size_t)v * 192 + l];
        float a1 = forceN[(size_t)v * 192 + 64 + l];
        float a2 = forceN[(size_t)v * 192 + 128 + l];
        for (int k = s; k < e; ++k) {
            const uint4 md = meta[k];
            const float e1v = e1a[(size_t)k * FDIM + l];
            const float e2v = e2a[(size_t)k * FDIM + l];
            const float* fd = forceN + (size_t)md.x * 192;
            a0 += e1v * __uint_as_float(md.y) + e2v * fd[l];
            a1 += e1v * __uint_as_float(md.z) + e2v * fd[64 + l];
            a2 += e1v * __uint_as_float(md.w) + e2v * fd[128 + l];
        }
        forceOut[(size_t)v * 192 + l] = a0;
        forceOut[(size_t)v * 192 + 64 + l] = a1;
        forceOut[(size_t)v * 192 + 128 + l] = a2;
        // inv_update2 + LayerNorm (fused)
        float r0 = 0.0f, r1 = 0.0f, r2 = 0.0f;
#pragma unroll 8
        for (int g = 0; g < FDIM; ++g) {
            const float w = Wus[g][l];
            r0 += bcast_lane(a0, g) * w;
            r1 += bcast_lane(a1, g) * w;
            r2 += bcast_lane(a2, g) * w;
        }
        float a = atomOut[(size_t)v * FDIM + l] + (a0 * r0 + a1 * r1 + a2 * r2);
        float ss = a;
#pragma unroll
        for (int off = 32; off >= 1; off >>= 1) ss += __shfl_xor(ss, off, 64);
        const float mu = ss * (1.0f / 64.0f);
        const float d = a - mu;
        float vv = d * d;
#pragma unroll
        for (int off = 32; off >= 1; off >>= 1) vv += __shfl_xor(vv, off, 64);
        vv *= (1.0f / 64.0f);
        atomOut[(size_t)v * FDIM + l] = d * rsqrtf(vv + LN_EPS) * gg + bb;
    }
}

// ---------------- Fallback: R13 fused edge kernel + node_final ----------------
__global__ __launch_bounds__(64 * NW, 2) void edge_kernel_fused(
    const float* __restrict__ dist, const float* __restrict__ dir,
    const int* __restrict__ eidx, const float* __restrict__ mn,
    const float* __restrict__ We,
    const float* __restrict__ Wq1a, const float* __restrict__ Wq1b,
    const float* __restrict__ Wq2a, const float* __restrict__ Wq2b,
    const float* __restrict__ forceN,
    float* __restrict__ atomAcc, float* __restrict__ forceAcc)
{
    __shared__ __align__(16) unsigned Bfr[16384];
    __shared__ __align__(16) unsigned WeFr[2048];
    __shared__ __align__(16) unsigned Astg[NW][16][76];

    const int l = threadIdx.x;
    const int ty = threadIdx.y;
    const int q = l >> 4, row = l & 15;

    for (int t = ty; t < 32; t += NW) {
        const int mm = t >> 3, kh = (t >> 2) & 1, c = t & 3;
        const float* W = (mm == 0) ? Wq1a : (mm == 1) ? Wq2a : (mm == 2) ? Wq1b : Wq2b;
        const int n = c * 16 + row;
        const int kb = kh * 32 + q * 8;
        unsigned* hiP = &Bfr[(((mm * 2 + 0) * 2 + kh) * 4 + c) * 256 + l * 4];
        unsigned* loP = &Bfr[(((mm * 2 + 1) * 2 + kh) * 4 + c) * 256 + l * 4];
#pragma unroll
        for (int i = 0; i < 4; ++i) {
            float w0 = W[(kb + 2 * i) * FDIM + n];
            float w1 = W[(kb + 2 * i + 1) * FDIM + n];
            unsigned h0 = bf16_rn(w0);
            unsigned l0 = bf16_rn(w0 - __uint_as_float(h0 << 16));
            unsigned h1 = bf16_rn(w1);
            unsigned l1 = bf16_rn(w1 - __uint_as_float(h1 << 16));
            hiP[i] = h0 | (h1 << 16);
            loP[i] = l0 | (l1 << 16);
        }
    }
    for (int c = ty; c < 4; c += NW) {
        const int n = c * 16 + row;
        unsigned* hiP = &WeFr[(0 * 4 + c) * 256 + l * 4];
        unsigned* loP = &WeFr[(1 * 4 + c) * 256 + l * 4];
#pragma unroll
        for (int i = 0; i < 4; ++i) {
            const int k0 = q * 8 + 2 * i, k1 = k0 + 1;
            float w0 = (k0 < NB) ? We[k0 * FDIM + n] : 0.0f;
            float w1 = (k1 < NB) ? We[k1 * FDIM + n] : 0.0f;
            unsigned h0 = bf16_rn(w0);
            unsigned l0 = bf16_rn(w0 - __uint_as_float(h0 << 16));
            unsigned h1 = bf16_rn(w1);
            unsigned l1 = bf16_rn(w1 - __uint_as_float(h1 << 16));
            hiP[i] = h0 | (h1 << 16);
            loP[i] = l0 | (l1 << 16);
        }
    }
    __syncthreads();

    const unsigned* B1aH = Bfr + 0 * 2048; const unsigned* B1aL = Bfr + 1 * 2048;
    const unsigned* B2aH = Bfr + 2 * 2048; const unsigned* B2aL = Bfr + 3 * 2048;
    const unsigned* B1bH = Bfr + 4 * 2048; const unsigned* B1bL = Bfr + 5 * 2048;
    const unsigned* B2bH = Bfr + 6 * 2048; const unsigned* B2bL = Bfr + 7 * 2048;
    const unsigned* WeH = WeFr;            const unsigned* WeL = WeFr + 1024;

    unsigned* stg = &Astg[ty][0][0];
    const unsigned* rowPtr = &Astg[ty][row][0];

    const int ngroups = N_EDGES / 16;
    const int stride = gridDim.x * NW;
    for (int grp = blockIdx.x * NW + ty; grp < ngroups; grp += stride) {
        const int e0 = grp * 16;
        int ev = 0;
        if (l < 32) ev = eidx[(l < 16) ? (e0 + l) : (N_EDGES + e0 + (l - 16))];
        float dv = (l < 48) ? dir[e0 * 3 + l] : 0.0f;

        const float* dp = dist + (size_t)(e0 + row) * NB + q * 8;
        float4 da = {0.f, 0.f, 0.f, 0.f}, db = {0.f, 0.f, 0.f, 0.f};
        if (q < 2)       { da = *(const float4*)dp; db = *(const float4*)(dp + 4); }
        else if (q == 2) { da = *(const float4*)dp; }
        unsigned s0 = pack_split(da.x), s1 = pack_split(da.y);
        unsigned s2 = pack_split(da.z), s3 = pack_split(da.w);
        unsigned s4 = pack_split(db.x), s5 = pack_split(db.y);
        unsigned s6 = pack_split(db.z), s7 = pack_split(db.w);
        union { unsigned u[4]; bf16x8 v; } AH, AL;
        AH.u[0] = __builtin_amdgcn_perm(s1, s0, SEL_HI);
        AH.u[1] = __builtin_amdgcn_perm(s3, s2, SEL_HI);
        AH.u[2] = __builtin_amdgcn_perm(s5, s4, SEL_HI);
        AH.u[3] = __builtin_amdgcn_perm(s7, s6, SEL_HI);
        AL.u[0] = __builtin_amdgcn_perm(s1, s0, SEL_LO);
        AL.u[1] = __builtin_amdgcn_perm(s3, s2, SEL_LO);
        AL.u[2] = __builtin_amdgcn_perm(s5, s4, SEL_LO);
        AL.u[3] = __builtin_amdgcn_perm(s7, s6, SEL_LO);

        f32x4 me4[4];
#pragma unroll
        for (int c = 0; c < 4; ++c) me4[c] = (f32x4){0.f, 0.f, 0.f, 0.f};
        mm3(WeH, WeL, AH.v, AL.v, me4, 0, l);
#pragma unroll
        for (int c = 0; c < 4; ++c)
#pragma unroll
            for (int r = 0; r < 4; ++r)
                stg[(q * 4 + r) * 76 + (row + 16 * c)] = __float_as_uint(me4[c][r]);

        float p[16];
#pragma unroll
        for (int j = 0; j < 16; ++j) {
            const int src = __builtin_amdgcn_readlane(ev, j);
            const int dst = __builtin_amdgcn_readlane(ev, 16 + j);
            p[j] = mn[(size_t)src * FDIM + l] * mn[(size_t)dst * FDIM + l];
        }
#pragma unroll
        for (int j = 0; j < 16; ++j) {
            const int src = __builtin_amdgcn_readlane(ev, j);
            const float m = __uint_as_float(stg[j * 76 + l]) * p[j];
            atomicAdd(&atomAcc[(size_t)src * FDIM + l], m);
            stg[j * 76 + l] = pack_split(m);
        }

        f32x4 acc1[4], acc2[4];
#pragma unroll
        for (int c = 0; c < 4; ++c) {
            acc1[c] = (f32x4){0.f, 0.f, 0.f, 0.f};
            acc2[c] = (f32x4){0.f, 0.f, 0.f, 0.f};
        }
#pragma unroll
        for (int kh = 0; kh < 2; ++kh) {
            bf16x8 ahi, alo;
            load_afrag(rowPtr, kh, q, &ahi, &alo);
            mm3(B1aH, B1aL, ahi, alo, acc1, kh, l);
            mm3(B2aH, B2aL, ahi, alo, acc2, kh, l);
        }
#pragma unroll
        for (int c = 0; c < 4; ++c)
#pragma unroll
            for (int r = 0; r < 4; ++r) {
                acc1[c][r] = silu_f(acc1[c][r]);
                acc2[c][r] = silu_f(acc2[c][r]);
            }
#pragma unroll
        for (int c = 0; c < 4; ++c)
#pragma unroll
            for (int r = 0; r < 4; ++r)
                stg[(q * 4 + r) * 76 + (row + 16 * c)] = pack_split(acc1[c][r]);
        f32x4 eacc1[4];
#pragma unroll
        for (int c = 0; c < 4; ++c) eacc1[c] = (f32x4){0.f, 0.f, 0.f, 0.f};
#pragma unroll
        for (int kh = 0; kh < 2; ++kh) {
            bf16x8 ahi, alo;
            load_afrag(rowPtr, kh, q, &ahi, &alo);
            mm3(B1bH, B1bL, ahi, alo, eacc1, kh, l);
        }
#pragma unroll
        for (int c = 0; c < 4; ++c)
#pragma unroll
            for (int r = 0; r < 4; ++r)
                stg[(q * 4 + r) * 76 + (row + 16 * c)] = pack_split(acc2[c][r]);
        f32x4 eacc2[4];
#pragma unroll
        for (int c = 0; c < 4; ++c) eacc2[c] = (f32x4){0.f, 0.f, 0.f, 0.f};
#pragma unroll
        for (int kh = 0; kh < 2; ++kh) {
            bf16x8 ahi, alo;
            load_afrag(rowPtr, kh, q, &ahi, &alo);
            mm3(B2bH, B2bL, ahi, alo, eacc2, kh, l);
        }
#pragma unroll
        for (int r = 0; r < 4; ++r) {
            const int eo = q * 4 + r;
            const int vs = __shfl(ev, eo);
            const int vd = __shfl(ev, 16 + eo);
            const float d0 = __shfl(dv, eo * 3 + 0);
            const float d1 = __shfl(dv, eo * 3 + 1);
            const float d2 = __shfl(dv, eo * 3 + 2);
            const float* fd = forceN + (size_t)vd * 3 * FDIM;
            float* fa = forceAcc + (size_t)vs * 3 * FDIM;
#pragma unroll
            for (int c = 0; c < 4; ++c) {
                const int n = row + 16 * c;
                atomicAdd(&fa[0 * FDIM + n], eacc1[c][r] * d0 + eacc2[c][r] * fd[0 * FDIM + n]);
                atomicAdd(&fa[1 * FDIM + n], eacc1[c][r] * d1 + eacc2[c][r] * fd[1 * FDIM + n]);
                atomicAdd(&fa[2 * FDIM + n], eacc1[c][r] * d2 + eacc2[c][r] * fd[2 * FDIM + n]);
            }
        }
    }
}

__global__ __launch_bounds__(256) void node_final_kernel(
    const float* __restrict__ Wu, const float* __restrict__ gamma, const float* __restrict__ beta,
    float* __restrict__ atomAcc, const float* __restrict__ forceOut)
{
    __shared__ float Wus[FDIM][FDIM];
    const int f = threadIdx.x, ty = threadIdx.y;
    const int tid = ty * 64 + f;
    for (int i = tid; i < FDIM * FDIM; i += 256) ((float*)Wus)[i] = Wu[i];
    __syncthreads();
    const float gg = gamma[f], bb = beta[f];
    const int nw = gridDim.x * 4;
    for (int n = blockIdx.x * 4 + ty; n < N_NODES; n += nw) {
        const float f0 = forceOut[((size_t)n * 3 + 0) * FDIM + f];
        const float f1 = forceOut[((size_t)n * 3 + 1) * FDIM + f];
        const float f2 = forceOut[((size_t)n * 3 + 2) * FDIM + f];
        float r0 = 0.0f, r1 = 0.0f, r2 = 0.0f;
#pragma unroll 8
        for (int g = 0; g < FDIM; ++g) {
            const float w = Wus[g][f];
            r0 += bcast_lane(f0, g) * w;
            r1 += bcast_lane(f1, g) * w;
            r2 += bcast_lane(f2, g) * w;
        }
        float a = atomAcc[n * FDIM + f] + (f0 * r0 + f1 * r1 + f2 * r2);
        float s = a;
#pragma unroll
        for (int off = 32; off >= 1; off >>= 1) s += __shfl_xor(s, off, 64);
        const float mu = s * (1.0f / 64.0f);
        const float d = a - mu;
        float v = d * d;
#pragma unroll
        for (int off = 32; off >= 1; off >>= 1) v += __shfl_xor(v, off, 64);
        v *= (1.0f / 64.0f);
        atomAcc[n * FDIM + f] = d * rsqrtf(v + LN_EPS) * gg + bb;
    }
}

extern "C" void kernel_launch(void* const* d_in, const int* in_sizes, int n_in,
                              void* d_out, int out_size, void* d_ws, size_t ws_size,
                              hipStream_t stream)
{
    const float* atom_node  = (const float*)d_in[0];
    const float* force_node = (const float*)d_in[1];
    const float* dir_edge   = (const float*)d_in[2];
    const float* dist_edge  = (const float*)d_in[3];
    const int*   edge_index = (const int*)d_in[4];
    const float* W1   = (const float*)d_in[5];
    const float* b1   = (const float*)d_in[6];
    const float* W2   = (const float*)d_in[7];
    const float* b2   = (const float*)d_in[8];
    const float* We   = (const float*)d_in[9];
    const float* Wq1a = (const float*)d_in[10];
    const float* Wq1b = (const float*)d_in[11];
    const float* Wq2a = (const float*)d_in[12];
    const float* Wq2b = (const float*)d_in[13];
    const float* Wu   = (const float*)d_in[14];
    const float* gamma = (const float*)d_in[15];
    const float* beta  = (const float*)d_in[16];

    float* atomOut  = (float*)d_out;
    float* forceOut = (float*)d_out + (size_t)N_NODES * FDIM;

    // ws layout (byte offsets, 16-aligned):
    //   mn        0          .. 5,120,000
    //   cursor    5,120,000  .. 5,200,000
    //   rowStart  5,200,000  .. 5,280,016   (20001 ints)
    //   invperm   5,280,016  .. 7,840,016   (pad to 7,840,032)
    //   meta      7,840,032  .. 18,080,032  (E x 16B)
    //   e1        18,080,032 .. 181,920,032
    //   e2        181,920,032.. 345,760,032
    char* ws = (char*)d_ws;
    float* mn      = (float*)ws;
    int*   cursor  = (int*)(ws + 5120000);
    int*   rowStart= (int*)(ws + 5200000);
    int*   invperm = (int*)(ws + 5280016);
    uint4* meta    = (uint4*)(ws + 7840032);
    float* e1a     = (float*)(ws + 18080032);
    float* e2a     = (float*)(ws + 181920032ull);
    const size_t NEED = 345760032ull;

    dim3 blk4(64, 4);
    dim3 blkE(64, NW);
    dim3 blkP2(64, 8);

    hipMemcpyAsync(atomOut, atom_node, (size_t)N_NODES * FDIM * sizeof(float),
                   hipMemcpyDeviceToDevice, stream);
    node_mlp_kernel<<<512, blk4, 0, stream>>>(atom_node, W1, b1, W2, b2, mn);

    if (ws_size >= NEED) {
        // two-phase path: no force atomics
        hipMemsetAsync(cursor, 0, N_NODES * sizeof(int), stream);
        hist_kernel<<<1024, 256, 0, stream>>>(edge_index, cursor);
        scan_kernel<<<1, 1024, 0, stream>>>(cursor, rowStart);
        permute_kernel<<<1024, 256, 0, stream>>>(edge_index, dir_edge, cursor, invperm, meta);
        edge_p1_kernel<<<256, blkE, 0, stream>>>(dist_edge, edge_index, invperm, mn, We,
                                                 Wq1a, Wq1b, Wq2a, Wq2b,
                                                 atomOut, e1a, e2a);
        node_p2_kernel<<<512, blkP2, 0, stream>>>(force_node, Wu, gamma, beta,
                                                  meta, rowStart, e1a, e2a,
                                                  atomOut, forceOut);
    } else {
        // fallback: R13 path
        hipMemcpyAsync(forceOut, force_node, (size_t)N_NODES * 3 * FDIM * sizeof(float),
                       hipMemcpyDeviceToDevice, stream);
        edge_kernel_fused<<<256, blkE, 0, stream>>>(dist_edge, dir_edge, edge_index, mn, We,
                                                    Wq1a, Wq1b, Wq2a, Wq2b, force_node,
                                                    atomOut, forceOut);
        node_final_kernel<<<512, blk4, 0, stream>>>(Wu, gamma, beta, atomOut, forceOut);
    }
}

// Round 16
// 541.248 us; speedup vs baseline: 1.1567x; 1.1567x over previous
//
#include <hip/hip_runtime.h>
#include <hip/hip_fp16.h>

#define N_NODES 20000
#define N_EDGES 640000
#define FDIM 64
#define NB 20
#define LN_EPS 1e-5f
#define NW 8

typedef __attribute__((ext_vector_type(8))) short bf16x8;
typedef __attribute__((ext_vector_type(4))) float f32x4;

#define SEL_HI 0x07060302u
#define SEL_LO 0x05040100u
#define MFMA16 __builtin_amdgcn_mfma_f32_16x16x32_bf16

__device__ __forceinline__ float silu_f(float x) { return x / (1.0f + __expf(-x)); }

__device__ __forceinline__ float bcast_lane(float v, int lane) {
    return __int_as_float(__builtin_amdgcn_readlane(__float_as_int(v), lane));
}

__device__ __forceinline__ unsigned bf16_rn(float x) {
    unsigned u = __float_as_uint(x);
    return (u + 0x7FFFu + ((u >> 16) & 1u)) >> 16;
}

__device__ __forceinline__ unsigned pack_split(float x) {
    unsigned h = bf16_rn(x);
    unsigned lo = bf16_rn(x - __uint_as_float(h << 16));
    return (h << 16) | lo;
}

// packed fp16 atomic add: emits global_atomic_pk_add_f16 on gfx9xx
__device__ __forceinline__ void pk_atomic_add(__half2* addr, float a, float b) {
    unsafeAtomicAdd(addr, __floats2half2_rn(a, b));
}

__device__ __forceinline__ void load_afrag(const unsigned* rowPtr, int kh, int q,
                                           bf16x8* ahi, bf16x8* alo) {
    const uint4 ra = *(const uint4*)(rowPtr + kh * 32 + q * 8);
    const uint4 rb = *(const uint4*)(rowPtr + kh * 32 + q * 8 + 4);
    union { unsigned u[4]; bf16x8 v; } H, L;
    H.u[0] = __builtin_amdgcn_perm(ra.y, ra.x, SEL_HI);
    H.u[1] = __builtin_amdgcn_perm(ra.w, ra.z, SEL_HI);
    H.u[2] = __builtin_amdgcn_perm(rb.y, rb.x, SEL_HI);
    H.u[3] = __builtin_amdgcn_perm(rb.w, rb.z, SEL_HI);
    L.u[0] = __builtin_amdgcn_perm(ra.y, ra.x, SEL_LO);
    L.u[1] = __builtin_amdgcn_perm(ra.w, ra.z, SEL_LO);
    L.u[2] = __builtin_amdgcn_perm(rb.y, rb.x, SEL_LO);
    L.u[3] = __builtin_amdgcn_perm(rb.w, rb.z, SEL_LO);
    *ahi = H.v;
    *alo = L.v;
}

__device__ __forceinline__ void mm3(const unsigned* Bhi, const unsigned* Blo,
                                    bf16x8 ahi, bf16x8 alo, f32x4* acc, int kh, int l) {
#pragma unroll
    for (int c = 0; c < 4; ++c) {
        bf16x8 bh = *(const bf16x8*)(Bhi + (kh * 4 + c) * 256 + l * 4);
        bf16x8 bl = *(const bf16x8*)(Blo + (kh * 4 + c) * 256 + l * 4);
        acc[c] = MFMA16(ahi, bh, acc[c], 0, 0, 0);
        acc[c] = MFMA16(ahi, bl, acc[c], 0, 0, 0);
        acc[c] = MFMA16(alo, bh, acc[c], 0, 0, 0);
    }
}

// ---------------- Kernel A: node MLP ----------------
__global__ __launch_bounds__(256) void node_mlp_kernel(
    const float* __restrict__ atom, const float* __restrict__ W1, const float* __restrict__ b1,
    const float* __restrict__ W2, const float* __restrict__ b2, float* __restrict__ mn)
{
    __shared__ float W1s[FDIM][FDIM];
    __shared__ float W2s[FDIM][FDIM];
    const int f = threadIdx.x, ty = threadIdx.y;
    const int tid = ty * 64 + f;
    for (int i = tid; i < FDIM * FDIM; i += 256) {
        ((float*)W1s)[i] = W1[i];
        ((float*)W2s)[i] = W2[i];
    }
    __syncthreads();
    const float bb1 = b1[f], bb2 = b2[f];
    const int nw = gridDim.x * 4;
    for (int n = blockIdx.x * 4 + ty; n < N_NODES; n += nw) {
        const float a = atom[n * FDIM + f];
        float h = bb1;
        for (int g = 0; g < FDIM; ++g) h += bcast_lane(a, g) * W1s[g][f];
        h = silu_f(h);
        float o = bb2;
        for (int g = 0; g < FDIM; ++g) o += bcast_lane(h, g) * W2s[g][f];
        mn[n * FDIM + f] = o;
    }
}

// ---------------- Kernel B: per-edge MFMA pipeline, packed-fp16 atomics ----------------
// Updates accumulate via global_atomic_pk_add_f16 into small zero-init buffers:
//   aUpd [N][32] __half2 (inv_update1), fUpd [N][3][32] __half2 (force_update).
// Lane pairs exchange via shfl_xor(1); even lanes issue one packed atomic for 2 features.
// Per-edge atomic lane-ops 256 -> 128, touched lines 16 -> 8, footprint 660 MB -> 10 MB.
__global__ __launch_bounds__(64 * NW, 2) void edge_kernel(
    const float* __restrict__ dist,   // [E,20]
    const float* __restrict__ dir,    // [E,3]
    const int* __restrict__ eidx,     // [2,E] int32
    const float* __restrict__ mn,     // [N,F]
    const float* __restrict__ We,     // [20,F]
    const float* __restrict__ Wq1a, const float* __restrict__ Wq1b,
    const float* __restrict__ Wq2a, const float* __restrict__ Wq2b,
    const float* __restrict__ forceN, // [N,3,F]
    __half2* __restrict__ aUpd,       // [N*32], zero-init
    __half2* __restrict__ fUpd)       // [N*96], zero-init
{
    __shared__ __align__(16) unsigned Bfr[16384];
    __shared__ __align__(16) unsigned WeFr[2048];
    __shared__ __align__(16) unsigned Astg[NW][16][76];

    const int l = threadIdx.x;
    const int ty = threadIdx.y;
    const int q = l >> 4, row = l & 15;
    const bool evenLane = ((l & 1) == 0);

    for (int t = ty; t < 32; t += NW) {
        const int mm = t >> 3, kh = (t >> 2) & 1, c = t & 3;
        const float* W = (mm == 0) ? Wq1a : (mm == 1) ? Wq2a : (mm == 2) ? Wq1b : Wq2b;
        const int n = c * 16 + row;
        const int kb = kh * 32 + q * 8;
        unsigned* hiP = &Bfr[(((mm * 2 + 0) * 2 + kh) * 4 + c) * 256 + l * 4];
        unsigned* loP = &Bfr[(((mm * 2 + 1) * 2 + kh) * 4 + c) * 256 + l * 4];
#pragma unroll
        for (int i = 0; i < 4; ++i) {
            float w0 = W[(kb + 2 * i) * FDIM + n];
            float w1 = W[(kb + 2 * i + 1) * FDIM + n];
            unsigned h0 = bf16_rn(w0);
            unsigned l0 = bf16_rn(w0 - __uint_as_float(h0 << 16));
            unsigned h1 = bf16_rn(w1);
            unsigned l1 = bf16_rn(w1 - __uint_as_float(h1 << 16));
            hiP[i] = h0 | (h1 << 16);
            loP[i] = l0 | (l1 << 16);
        }
    }
    for (int c = ty; c < 4; c += NW) {
        const int n = c * 16 + row;
        unsigned* hiP = &WeFr[(0 * 4 + c) * 256 + l * 4];
        unsigned* loP = &WeFr[(1 * 4 + c) * 256 + l * 4];
#pragma unroll
        for (int i = 0; i < 4; ++i) {
            const int k0 = q * 8 + 2 * i, k1 = k0 + 1;
            float w0 = (k0 < NB) ? We[k0 * FDIM + n] : 0.0f;
            float w1 = (k1 < NB) ? We[k1 * FDIM + n] : 0.0f;
            unsigned h0 = bf16_rn(w0);
            unsigned l0 = bf16_rn(w0 - __uint_as_float(h0 << 16));
            unsigned h1 = bf16_rn(w1);
            unsigned l1 = bf16_rn(w1 - __uint_as_float(h1 << 16));
            hiP[i] = h0 | (h1 << 16);
            loP[i] = l0 | (l1 << 16);
        }
    }
    __syncthreads();

    const unsigned* B1aH = Bfr + 0 * 2048; const unsigned* B1aL = Bfr + 1 * 2048;
    const unsigned* B2aH = Bfr + 2 * 2048; const unsigned* B2aL = Bfr + 3 * 2048;
    const unsigned* B1bH = Bfr + 4 * 2048; const unsigned* B1bL = Bfr + 5 * 2048;
    const unsigned* B2bH = Bfr + 6 * 2048; const unsigned* B2bL = Bfr + 7 * 2048;
    const unsigned* WeH = WeFr;            const unsigned* WeL = WeFr + 1024;

    unsigned* stg = &Astg[ty][0][0];
    const unsigned* rowPtr = &Astg[ty][row][0];

    const int ngroups = N_EDGES / 16;
    const int stride = gridDim.x * NW;
    for (int grp = blockIdx.x * NW + ty; grp < ngroups; grp += stride) {
        const int e0 = grp * 16;

        int ev = 0;
        if (l < 32) ev = eidx[(l < 16) ? (e0 + l) : (N_EDGES + e0 + (l - 16))];
        float dv = (l < 48) ? dir[e0 * 3 + l] : 0.0f;

        // ---- me = dist16x20 @ We20x64 via MFMA ----
        const float* dp = dist + (size_t)(e0 + row) * NB + q * 8;
        float4 da = {0.f, 0.f, 0.f, 0.f}, db = {0.f, 0.f, 0.f, 0.f};
        if (q < 2)       { da = *(const float4*)dp; db = *(const float4*)(dp + 4); }
        else if (q == 2) { da = *(const float4*)dp; }
        unsigned s0 = pack_split(da.x), s1 = pack_split(da.y);
        unsigned s2 = pack_split(da.z), s3 = pack_split(da.w);
        unsigned s4 = pack_split(db.x), s5 = pack_split(db.y);
        unsigned s6 = pack_split(db.z), s7 = pack_split(db.w);
        union { unsigned u[4]; bf16x8 v; } AH, AL;
        AH.u[0] = __builtin_amdgcn_perm(s1, s0, SEL_HI);
        AH.u[1] = __builtin_amdgcn_perm(s3, s2, SEL_HI);
        AH.u[2] = __builtin_amdgcn_perm(s5, s4, SEL_HI);
        AH.u[3] = __builtin_amdgcn_perm(s7, s6, SEL_HI);
        AL.u[0] = __builtin_amdgcn_perm(s1, s0, SEL_LO);
        AL.u[1] = __builtin_amdgcn_perm(s3, s2, SEL_LO);
        AL.u[2] = __builtin_amdgcn_perm(s5, s4, SEL_LO);
        AL.u[3] = __builtin_amdgcn_perm(s7, s6, SEL_LO);

        f32x4 me4[4];
#pragma unroll
        for (int c = 0; c < 4; ++c) me4[c] = (f32x4){0.f, 0.f, 0.f, 0.f};
        mm3(WeH, WeL, AH.v, AL.v, me4, 0, l);
#pragma unroll
        for (int c = 0; c < 4; ++c)
#pragma unroll
            for (int r = 0; r < 4; ++r)
                stg[(q * 4 + r) * 76 + (row + 16 * c)] = __float_as_uint(me4[c][r]);

        // ---- msg pass A: mn gathers only ----
        float p[16];
#pragma unroll
        for (int j = 0; j < 16; ++j) {
            const int src = __builtin_amdgcn_readlane(ev, j);
            const int dst = __builtin_amdgcn_readlane(ev, 16 + j);
            p[j] = mn[(size_t)src * FDIM + l] * mn[(size_t)dst * FDIM + l];
        }
        // ---- msg pass B: packed fp16 atomics (even lanes), no loads ----
#pragma unroll
        for (int j = 0; j < 16; ++j) {
            const int src = __builtin_amdgcn_readlane(ev, j);
            const float m = __uint_as_float(stg[j * 76 + l]) * p[j];
            const float mp = __shfl_xor(m, 1, 64);
            if (evenLane)
                pk_atomic_add(&aUpd[(size_t)src * 32 + (l >> 1)], m, mp);
            stg[j * 76 + l] = pack_split(m);
        }

        // ---- h-phase ----
        f32x4 acc1[4], acc2[4];
#pragma unroll
        for (int c = 0; c < 4; ++c) {
            acc1[c] = (f32x4){0.f, 0.f, 0.f, 0.f};
            acc2[c] = (f32x4){0.f, 0.f, 0.f, 0.f};
        }
#pragma unroll
        for (int kh = 0; kh < 2; ++kh) {
            bf16x8 ahi, alo;
            load_afrag(rowPtr, kh, q, &ahi, &alo);
            mm3(B1aH, B1aL, ahi, alo, acc1, kh, l);
            mm3(B2aH, B2aL, ahi, alo, acc2, kh, l);
        }
#pragma unroll
        for (int c = 0; c < 4; ++c)
#pragma unroll
            for (int r = 0; r < 4; ++r) {
                acc1[c][r] = silu_f(acc1[c][r]);
                acc2[c][r] = silu_f(acc2[c][r]);
            }

        // ---- e1 = h1@Wq1b ----
#pragma unroll
        for (int c = 0; c < 4; ++c)
#pragma unroll
            for (int r = 0; r < 4; ++r)
                stg[(q * 4 + r) * 76 + (row + 16 * c)] = pack_split(acc1[c][r]);
        f32x4 eacc1[4];
#pragma unroll
        for (int c = 0; c < 4; ++c) eacc1[c] = (f32x4){0.f, 0.f, 0.f, 0.f};
#pragma unroll
        for (int kh = 0; kh < 2; ++kh) {
            bf16x8 ahi, alo;
            load_afrag(rowPtr, kh, q, &ahi, &alo);
            mm3(B1bH, B1bL, ahi, alo, eacc1, kh, l);
        }

        // ---- e2 = h2@Wq2b ----
#pragma unroll
        for (int c = 0; c < 4; ++c)
#pragma unroll
            for (int r = 0; r < 4; ++r)
                stg[(q * 4 + r) * 76 + (row + 16 * c)] = pack_split(acc2[c][r]);
        f32x4 eacc2[4];
#pragma unroll
        for (int c = 0; c < 4; ++c) eacc2[c] = (f32x4){0.f, 0.f, 0.f, 0.f};
#pragma unroll
        for (int kh = 0; kh < 2; ++kh) {
            bf16x8 ahi, alo;
            load_afrag(rowPtr, kh, q, &ahi, &alo);
            mm3(B2bH, B2bL, ahi, alo, eacc2, kh, l);
        }

        // ---- scatter: per r-block, batch 12 fd loads, then packed fp16 atomics ----
#pragma unroll
        for (int r = 0; r < 4; ++r) {
            const int eo = q * 4 + r;
            const int vs = __shfl(ev, eo);
            const int vd = __shfl(ev, 16 + eo);
            const float d0 = __shfl(dv, eo * 3 + 0);
            const float d1 = __shfl(dv, eo * 3 + 1);
            const float d2 = __shfl(dv, eo * 3 + 2);
            const float* fd = forceN + (size_t)vd * 3 * FDIM;
            float f0[4], f1[4], f2[4];
#pragma unroll
            for (int c = 0; c < 4; ++c) {
                const int n = row + 16 * c;
                f0[c] = fd[0 * FDIM + n];
                f1[c] = fd[1 * FDIM + n];
                f2[c] = fd[2 * FDIM + n];
            }
            __half2* base = fUpd + (size_t)vs * 96;
#pragma unroll
            for (int c = 0; c < 4; ++c) {
                const float v0 = eacc1[c][r] * d0 + eacc2[c][r] * f0[c];
                const float v1 = eacc1[c][r] * d1 + eacc2[c][r] * f1[c];
                const float v2 = eacc1[c][r] * d2 + eacc2[c][r] * f2[c];
                const float p0 = __shfl_xor(v0, 1, 64);
                const float p1 = __shfl_xor(v1, 1, 64);
                const float p2 = __shfl_xor(v2, 1, 64);
                if (evenLane) {
                    const int idx = (row >> 1) + 8 * c;
                    pk_atomic_add(base + 0 * 32 + idx, v0, p0);
                    pk_atomic_add(base + 1 * 32 + idx, v1, p1);
                    pk_atomic_add(base + 2 * 32 + idx, v2, p2);
                }
            }
        }
    }
}

// ---------------- Kernel C: reconstruct outputs + inv_update2 + LayerNorm ----------------
__global__ __launch_bounds__(256) void node_final_kernel(
    const float* __restrict__ atomN,     // original atom_node [N,F]
    const float* __restrict__ forceN,    // original force_node [N,3,F]
    const __half2* __restrict__ aUpd,    // [N*32]
    const __half2* __restrict__ fUpd,    // [N*96]
    const float* __restrict__ Wu, const float* __restrict__ gamma, const float* __restrict__ beta,
    float* __restrict__ atomOut, float* __restrict__ forceOut)
{
    __shared__ float Wus[FDIM][FDIM];
    const int f = threadIdx.x, ty = threadIdx.y;
    const int tid = ty * 64 + f;
    for (int i = tid; i < FDIM * FDIM; i += 256) ((float*)Wus)[i] = Wu[i];
    __syncthreads();
    const float gg = gamma[f], bb = beta[f];
    const bool hi = (f & 1);
    const int nw = gridDim.x * 4;
    for (int n = blockIdx.x * 4 + ty; n < N_NODES; n += nw) {
        const __half2 u0 = fUpd[(size_t)n * 96 + 0 * 32 + (f >> 1)];
        const __half2 u1 = fUpd[(size_t)n * 96 + 1 * 32 + (f >> 1)];
        const __half2 u2 = fUpd[(size_t)n * 96 + 2 * 32 + (f >> 1)];
        const float f0 = forceN[((size_t)n * 3 + 0) * FDIM + f] + (hi ? __high2float(u0) : __low2float(u0));
        const float f1 = forceN[((size_t)n * 3 + 1) * FDIM + f] + (hi ? __high2float(u1) : __low2float(u1));
        const float f2 = forceN[((size_t)n * 3 + 2) * FDIM + f] + (hi ? __high2float(u2) : __low2float(u2));
        forceOut[((size_t)n * 3 + 0) * FDIM + f] = f0;
        forceOut[((size_t)n * 3 + 1) * FDIM + f] = f1;
        forceOut[((size_t)n * 3 + 2) * FDIM + f] = f2;

        float r0 = 0.0f, r1 = 0.0f, r2 = 0.0f;
#pragma unroll 8
        for (int g = 0; g < FDIM; ++g) {
            const float w = Wus[g][f];
            r0 += bcast_lane(f0, g) * w;
            r1 += bcast_lane(f1, g) * w;
            r2 += bcast_lane(f2, g) * w;
        }
        const __half2 ua = aUpd[(size_t)n * 32 + (f >> 1)];
        const float inv1 = hi ? __high2float(ua) : __low2float(ua);
        float a = atomN[(size_t)n * FDIM + f] + inv1 + (f0 * r0 + f1 * r1 + f2 * r2);
        float s = a;
#pragma unroll
        for (int off = 32; off >= 1; off >>= 1) s += __shfl_xor(s, off, 64);
        const float mu = s * (1.0f / 64.0f);
        const float d = a - mu;
        float v = d * d;
#pragma unroll
        for (int off = 32; off >= 1; off >>= 1) v += __shfl_xor(v, off, 64);
        v *= (1.0f / 64.0f);
        atomOut[(size_t)n * FDIM + f] = d * rsqrtf(v + LN_EPS) * gg + bb;
    }
}

extern "C" void kernel_launch(void* const* d_in, const int* in_sizes, int n_in,
                              void* d_out, int out_size, void* d_ws, size_t ws_size,
                              hipStream_t stream)
{
    const float* atom_node  = (const float*)d_in[0];
    const float* force_node = (const float*)d_in[1];
    const float* dir_edge   = (const float*)d_in[2];
    const float* dist_edge  = (const float*)d_in[3];
    const int*   edge_index = (const int*)d_in[4];
    const float* W1   = (const float*)d_in[5];
    const float* b1   = (const float*)d_in[6];
    const float* W2   = (const float*)d_in[7];
    const float* b2   = (const float*)d_in[8];
    const float* We   = (const float*)d_in[9];
    const float* Wq1a = (const float*)d_in[10];
    const float* Wq1b = (const float*)d_in[11];
    const float* Wq2a = (const float*)d_in[12];
    const float* Wq2b = (const float*)d_in[13];
    const float* Wu   = (const float*)d_in[14];
    const float* gamma = (const float*)d_in[15];
    const float* beta  = (const float*)d_in[16];

    float* atomOut  = (float*)d_out;
    float* forceOut = (float*)d_out + (size_t)N_NODES * FDIM;

    // ws layout: mn [0, 5.12MB) | aUpd [5.12, 7.68MB) | fUpd [7.68, 15.36MB)
    char* ws = (char*)d_ws;
    float*   mn   = (float*)ws;
    __half2* aUpd = (__half2*)(ws + 5120000);
    __half2* fUpd = (__half2*)(ws + 7680000);

    (void)hipMemsetAsync(aUpd, 0, (size_t)N_NODES * 32 * sizeof(__half2), stream);
    (void)hipMemsetAsync(fUpd, 0, (size_t)N_NODES * 96 * sizeof(__half2), stream);

    dim3 blk4(64, 4);
    dim3 blkE(64, NW);
    node_mlp_kernel<<<512, blk4, 0, stream>>>(atom_node, W1, b1, W2, b2, mn);
    edge_kernel<<<256, blkE, 0, stream>>>(dist_edge, dir_edge, edge_index, mn, We,
                                          Wq1a, Wq1b, Wq2a, Wq2b, force_node,
                                          aUpd, fUpd);
    node_final_kernel<<<512, blk4, 0, stream>>>(atom_node, force_node, aUpd, fUpd,
                                                Wu, gamma, beta, atomOut, forceOut);
}